// Round 2
// baseline (233.380 us; speedup 1.0000x reference)
//
#include <hip/hip_runtime.h>

#define BB  4
#define LL  512
#define HID 256
#define PAi 32
#define OO  64

// -------- Kernel 1: h[b,l,p] = dot(hidden[b,l,:], W_in[p,:]) + b_in[p] --------
__global__ __launch_bounds__(256) void k_in(const float* __restrict__ hidden,
                                            const float* __restrict__ W_in,
                                            const float* __restrict__ b_in,
                                            float* __restrict__ h) {
    __shared__ float4 hid[8 * 64];  // 8 rows x 256 floats = 8 KB
    const int tid  = threadIdx.x;
    const int row0 = blockIdx.x * 8;  // row in [0, B*L)
    const float4* src = (const float4*)(hidden + (size_t)row0 * HID);
    hid[tid]       = src[tid];
    hid[tid + 256] = src[tid + 256];
    __syncthreads();
    const int p = tid & 31;
    const int r = tid >> 5;
    const float4* w = (const float4*)(W_in + (size_t)p * HID);
    float acc = 0.f;
#pragma unroll
    for (int k = 0; k < 64; ++k) {
        float4 hv = hid[r * 64 + k];
        float4 wv = w[k];
        acc += hv.x * wv.x + hv.y * wv.y + hv.z * wv.z + hv.w * wv.w;
    }
    h[(size_t)(row0 + r) * PAi + p] = acc + b_in[p];
}

// -------- Kernel 2: t[b,j,o,q] = sum_p h[b,j,p] * W_out[o, p*32+q] --------
__global__ __launch_bounds__(256) void k_mid(const float* __restrict__ h,
                                             const float* __restrict__ W_out,
                                             float* __restrict__ t) {
    __shared__ __attribute__((aligned(16))) float hst[PAi * 8];  // [p][r] transposed
    const int tid  = threadIdx.x;
    const int row0 = blockIdx.x * 8;
    {
        const int p = tid & 31, r = tid >> 5;
        hst[p * 8 + r] = h[(size_t)(row0 + r) * PAi + p];
    }
    __syncthreads();
    const int qg = tid & 7;
    const int o1 = tid >> 3;  // 0..31
    const float4* W4 = (const float4*)W_out;  // [O][PA][8] float4
    float4 accA[8], accB[8];
#pragma unroll
    for (int r = 0; r < 8; ++r) {
        accA[r] = float4{0, 0, 0, 0};
        accB[r] = float4{0, 0, 0, 0};
    }
#pragma unroll 4
    for (int p = 0; p < PAi; ++p) {
        float4 wa = W4[(o1 * PAi + p) * 8 + qg];
        float4 wb = W4[((o1 + 32) * PAi + p) * 8 + qg];
        float4 h1 = *(const float4*)&hst[p * 8];
        float4 h2 = *(const float4*)&hst[p * 8 + 4];
        float hr[8] = {h1.x, h1.y, h1.z, h1.w, h2.x, h2.y, h2.z, h2.w};
#pragma unroll
        for (int r = 0; r < 8; ++r) {
            accA[r].x += hr[r] * wa.x; accA[r].y += hr[r] * wa.y;
            accA[r].z += hr[r] * wa.z; accA[r].w += hr[r] * wa.w;
            accB[r].x += hr[r] * wb.x; accB[r].y += hr[r] * wb.y;
            accB[r].z += hr[r] * wb.z; accB[r].w += hr[r] * wb.w;
        }
    }
#pragma unroll
    for (int r = 0; r < 8; ++r) {
        float4* dst = (float4*)(t + (size_t)(row0 + r) * OO * PAi);
        dst[o1 * 8 + qg]        = accA[r];
        dst[(o1 + 32) * 8 + qg] = accB[r];
    }
}

// -------- Kernel 3: out[b,i,j,o] = dot(t[b,j,o,:], h[b,i,:]) + b_out[o] + pw[b,i,j,o] --------
// No LDS: h rows are wave-uniform -> scalar (SMEM) loads, broadcast via SGPR operand in FMA.
// Thread: o = tid&63, jj = tid>>6; t fragment (32 floats) lives in VGPRs.
#define TI 32
#define TJ 4
__global__ __launch_bounds__(256) void k_out(const float* __restrict__ t,
                                             const float* __restrict__ h,
                                             const float* __restrict__ pw,
                                             const float* __restrict__ b_out,
                                             float* __restrict__ out) {
    const int tid = threadIdx.x;
    const int b   = blockIdx.z;
    const int i0  = blockIdx.y * TI;
    const int j0  = blockIdx.x * TJ;
    const int o   = tid & 63;
    const int jj  = tid >> 6;
    const int j   = j0 + jj;

    // per-thread t fragment (32 VGPRs)
    float tq[PAi];
    {
        const float4* tp = (const float4*)(t + (((size_t)b * LL + j) * OO + o) * PAi);
#pragma unroll
        for (int k = 0; k < 8; ++k) {
            float4 v = tp[k];
            tq[4 * k] = v.x; tq[4 * k + 1] = v.y; tq[4 * k + 2] = v.z; tq[4 * k + 3] = v.w;
        }
    }
    const float bo = b_out[o];

    // wave-uniform h base (blockIdx-only) -> scalar loads
    const float* __restrict__ hbase = h + ((size_t)b * LL + i0) * PAi;
    size_t idx = (((size_t)b * LL + i0) * LL + j) * OO + o;

#pragma unroll 8
    for (int ii = 0; ii < TI; ++ii) {
        const float* __restrict__ hrow = hbase + ii * PAi;
        float acc = 0.f;
#pragma unroll
        for (int k = 0; k < PAi; ++k) acc = fmaf(tq[k], hrow[k], acc);
        out[idx] = acc + bo + pw[idx];
        idx += (size_t)LL * OO;
    }
}

extern "C" void kernel_launch(void* const* d_in, const int* in_sizes, int n_in,
                              void* d_out, int out_size, void* d_ws, size_t ws_size,
                              hipStream_t stream) {
    const float* hidden = (const float*)d_in[0];
    const float* pw     = (const float*)d_in[1];
    const float* W_in   = (const float*)d_in[2];
    const float* b_in   = (const float*)d_in[3];
    const float* W_out  = (const float*)d_in[4];
    const float* b_out  = (const float*)d_in[5];
    float* out = (float*)d_out;

    float* h = (float*)d_ws;                       // B*L*PA   = 65536 floats (256 KB)
    float* t = h + (size_t)BB * LL * PAi;          // B*L*O*PA = 4194304 floats (16 MB)

    k_in <<<dim3(BB * LL / 8), 256, 0, stream>>>(hidden, W_in, b_in, h);
    k_mid<<<dim3(BB * LL / 8), 256, 0, stream>>>(h, W_out, t);
    k_out<<<dim3(LL / TJ, LL / TI, BB), 256, 0, stream>>>(t, h, pw, b_out, out);
}

// Round 3
// 142.734 us; speedup vs baseline: 1.6351x; 1.6351x over previous
//
#include <hip/hip_runtime.h>

#define BB  4
#define LL  512
#define HID 256
#define PAi 32
#define OO  64

using bf16x8 = __attribute__((ext_vector_type(8))) short;
using f32x4  = __attribute__((ext_vector_type(4))) float;

__device__ inline ushort f2bf(float x) {
    union { float f; unsigned u; } v; v.f = x;
    unsigned r = (v.u + 0x7fff + ((v.u >> 16) & 1)) >> 16;  // RNE
    return (ushort)r;
}

// -------- Kernel 1: h[b,l,p] = dot(hidden[b,l,:], W_in[p,:]) + b_in[p]; f32 + bf16 copies --------
__global__ __launch_bounds__(256) void k_in(const float* __restrict__ hidden,
                                            const float* __restrict__ W_in,
                                            const float* __restrict__ b_in,
                                            float* __restrict__ h,
                                            ushort* __restrict__ hb) {
    __shared__ float4 hid[8 * 64];  // 8 rows x 256 floats = 8 KB
    const int tid  = threadIdx.x;
    const int row0 = blockIdx.x * 8;  // row in [0, B*L)
    const float4* src = (const float4*)(hidden + (size_t)row0 * HID);
    hid[tid]       = src[tid];
    hid[tid + 256] = src[tid + 256];
    __syncthreads();
    const int p = tid & 31;
    const int r = tid >> 5;
    const float4* w = (const float4*)(W_in + (size_t)p * HID);
    float acc = 0.f;
#pragma unroll
    for (int k = 0; k < 64; ++k) {
        float4 hv = hid[r * 64 + k];
        float4 wv = w[k];
        acc += hv.x * wv.x + hv.y * wv.y + hv.z * wv.z + hv.w * wv.w;
    }
    const float val = acc + b_in[p];
    h[(size_t)(row0 + r) * PAi + p]  = val;
    hb[(size_t)(row0 + r) * PAi + p] = f2bf(val);
}

// -------- Kernel 2: t[b,j,o,q] = sum_p h[b,j,p] * W_out[o, p*32+q]  (bf16 out) --------
__global__ __launch_bounds__(256) void k_mid(const float* __restrict__ h,
                                             const float* __restrict__ W_out,
                                             ushort* __restrict__ t) {
    __shared__ __attribute__((aligned(16))) float hst[PAi * 8];  // [p][r] transposed
    const int tid  = threadIdx.x;
    const int row0 = blockIdx.x * 8;
    {
        const int p = tid & 31, r = tid >> 5;
        hst[p * 8 + r] = h[(size_t)(row0 + r) * PAi + p];
    }
    __syncthreads();
    const int qg = tid & 7;
    const int o1 = tid >> 3;  // 0..31
    const float4* W4 = (const float4*)W_out;  // [O][PA][8] float4
    float4 accA[8], accB[8];
#pragma unroll
    for (int r = 0; r < 8; ++r) {
        accA[r] = float4{0, 0, 0, 0};
        accB[r] = float4{0, 0, 0, 0};
    }
#pragma unroll 4
    for (int p = 0; p < PAi; ++p) {
        float4 wa = W4[(o1 * PAi + p) * 8 + qg];
        float4 wb = W4[((o1 + 32) * PAi + p) * 8 + qg];
        float4 h1 = *(const float4*)&hst[p * 8];
        float4 h2 = *(const float4*)&hst[p * 8 + 4];
        float hr[8] = {h1.x, h1.y, h1.z, h1.w, h2.x, h2.y, h2.z, h2.w};
#pragma unroll
        for (int r = 0; r < 8; ++r) {
            accA[r].x += hr[r] * wa.x; accA[r].y += hr[r] * wa.y;
            accA[r].z += hr[r] * wa.z; accA[r].w += hr[r] * wa.w;
            accB[r].x += hr[r] * wb.x; accB[r].y += hr[r] * wb.y;
            accB[r].z += hr[r] * wb.z; accB[r].w += hr[r] * wb.w;
        }
    }
#pragma unroll
    for (int r = 0; r < 8; ++r) {
        ushort4 ua, ub;
        ua.x = f2bf(accA[r].x); ua.y = f2bf(accA[r].y); ua.z = f2bf(accA[r].z); ua.w = f2bf(accA[r].w);
        ub.x = f2bf(accB[r].x); ub.y = f2bf(accB[r].y); ub.z = f2bf(accB[r].z); ub.w = f2bf(accB[r].w);
        ushort* dst = t + (size_t)(row0 + r) * OO * PAi;
        *(ushort4*)(dst + (o1 * 8 + qg) * 4)        = ua;
        *(ushort4*)(dst + ((o1 + 32) * 8 + qg) * 4) = ub;
    }
}

// -------- Kernel 3: out[b,i,jo] = sum_q h[b,i,q]*t[b,jo,q] + b_out[jo&63] + pw  (MFMA bf16) --------
// Per b: GEMM M=512 (i), N=32768 (jo=j*64+o), K=32. One 16x16x32 MFMA per 16x16 tile.
// A lane l: m=l&15, k=(l>>4)*8+e  -> h_bf16 row-major. B lane l: n=l&15, k=(l>>4)*8+e -> t_bf16 row-major.
// C/D: col=l&15, row=(l>>4)*4+reg (m89-verified).
#define NT 8   // jo-tiles per wave
__global__ __launch_bounds__(256) void k_out(const ushort* __restrict__ t,   // bf16 [B][L][OO][PAi]
                                             const ushort* __restrict__ hb,  // bf16 [B][L][PAi]
                                             const float* __restrict__ pw,
                                             const float* __restrict__ b_out,
                                             float* __restrict__ out) {
    const int tid  = threadIdx.x;
    const int lane = tid & 63;
    const int wave = tid >> 6;
    const int b    = blockIdx.z;
    const int i0   = blockIdx.y * 16;
    const int jo0  = blockIdx.x * (NT * 16 * 4) + wave * (NT * 16);  // multiple of 128

    const int l15 = lane & 15;
    const int g   = lane >> 4;  // 0..3

    // A fragment (reused across the whole jo strip)
    const bf16x8 afrag = *(const bf16x8*)(hb + ((size_t)(b * LL + i0 + l15)) * PAi + g * 8);

    // bias for the 4 o-phases (jo0 % 64 == 0)
    float bo[4];
#pragma unroll
    for (int c = 0; c < 4; ++c) bo[c] = b_out[c * 16 + l15];

    const size_t obase = ((size_t)(b * LL + i0)) * (LL * OO) + jo0;
    const ushort* tbase = t + ((size_t)b * LL * OO + jo0) * PAi + (size_t)l15 * PAi + g * 8;

#pragma unroll
    for (int tt = 0; tt < NT; ++tt) {
        const bf16x8 bfrag = *(const bf16x8*)(tbase + (size_t)tt * 16 * PAi);
        const size_t a0 = obase + (size_t)tt * 16 + l15 + (size_t)(g * 4) * (LL * OO);
        float pv[4];
#pragma unroll
        for (int r = 0; r < 4; ++r) pv[r] = pw[a0 + (size_t)r * (LL * OO)];
        f32x4 acc = {0.f, 0.f, 0.f, 0.f};
        acc = __builtin_amdgcn_mfma_f32_16x16x32_bf16(afrag, bfrag, acc, 0, 0, 0);
        const float bb = bo[tt & 3];
#pragma unroll
        for (int r = 0; r < 4; ++r) out[a0 + (size_t)r * (LL * OO)] = acc[r] + bb + pv[r];
    }
}

extern "C" void kernel_launch(void* const* d_in, const int* in_sizes, int n_in,
                              void* d_out, int out_size, void* d_ws, size_t ws_size,
                              hipStream_t stream) {
    const float* hidden = (const float*)d_in[0];
    const float* pw     = (const float*)d_in[1];
    const float* W_in   = (const float*)d_in[2];
    const float* b_in   = (const float*)d_in[3];
    const float* W_out  = (const float*)d_in[4];
    const float* b_out  = (const float*)d_in[5];
    float* out = (float*)d_out;

    float*  h  = (float*)d_ws;                      // 65536 f32  (256 KB)
    ushort* hb = (ushort*)(h + (size_t)BB * LL * PAi);        // 65536 bf16 (128 KB)
    ushort* tb = hb + (size_t)BB * LL * PAi;                  // 4194304 bf16 (8 MB)

    k_in <<<dim3(BB * LL / 8), 256, 0, stream>>>(hidden, W_in, b_in, h, hb);
    k_mid<<<dim3(BB * LL / 8), 256, 0, stream>>>(h, W_out, tb);
    // jo = 32768 per (b,i); each block covers 4 waves * NT tiles * 16 = 512 jo
    k_out<<<dim3(LL * OO / (NT * 16 * 4), LL / 16, BB), 256, 0, stream>>>(tb, hb, pw, b_out, out);
}